// Round 2
// baseline (957.863 us; speedup 1.0000x reference)
//
#include <hip/hip_runtime.h>

// GraphAttention: N=12288, IN=OUT=128.
// e_new = emb@W.T ; s = e_new@a1 ; t = e_new@a2
// e[i][j] = leaky(s_i + t_j) masked by adj; softmax rows; out = relu(att @ e_new)
//
//  k1: bf16 MFMA gemm emb@W.T -> Vt (bf16, transposed [d][j]); s,t stored
//      PRE-SCALED by log2(e) so k2 runs softmax in exp2 domain.
//  ktmax: TmaxK = max_j tK_j (exact row-max softmax shift; leaky is monotonic)
//  k2: streaming masked-softmax-PV, ZERO LDS / ZERO barriers.
//      Round-1 lesson: both LDS-staged variants (coalesced-repack and
//      global_load_lds ring) measured identical — the barrier-per-chunk
//      lockstep was the cost, not the load path. Vt is 3 MB = L2-resident
//      (guide: don't LDS-stage cache-fit data); adj/t/Vt all read direct,
//      waves free-run, adj double-buffered in regs 1 chunk ahead.
//      XCD swizzle: cs = bid%8 -> each XCD's L2 owns one 393KB Vt slice.
//  k3: reduce col-split partials + denominators + normalize + relu.

#define NN 12288
#define DIM 128
#define CSPLIT 8
#define COLS_PER (NN / CSPLIT)   // 1536
#define BK 32
#define NCHUNK (COLS_PER / BK)   // 48
#define LOG2E 1.4426950408889634f

typedef __bf16 bf16x8 __attribute__((ext_vector_type(8)));
typedef float f32x4 __attribute__((ext_vector_type(4)));

// ---------------- kernel 1: e_new = emb @ W.T (bf16 MFMA), emits Vt, sK, tK --
__global__ __launch_bounds__(256) void k1_gemm(const float* __restrict__ emb,
                                               const float* __restrict__ W,
                                               const float* __restrict__ a,
                                               __bf16* __restrict__ Vt,
                                               float* __restrict__ s,
                                               float* __restrict__ t) {
  const int lane = threadIdx.x & 63;
  const int wave = threadIdx.x >> 6;
  const int m = lane & 15;
  const int quad = lane >> 4;
  const int row0 = blockIdx.x * 64 + wave * 16;  // this wave: 16 rows

  f32x4 acc[8];
#pragma unroll
  for (int nb = 0; nb < 8; nb++) acc[nb] = (f32x4){0.f, 0.f, 0.f, 0.f};

#pragma unroll
  for (int ks = 0; ks < 4; ks++) {
    const int k0 = ks * 32 + quad * 8;
    const float* ep = emb + (size_t)(row0 + m) * DIM + k0;
    float4 lo = *(const float4*)ep;
    float4 hi = *(const float4*)(ep + 4);
    bf16x8 af = {(__bf16)lo.x, (__bf16)lo.y, (__bf16)lo.z, (__bf16)lo.w,
                 (__bf16)hi.x, (__bf16)hi.y, (__bf16)hi.z, (__bf16)hi.w};
#pragma unroll
    for (int nb = 0; nb < 8; nb++) {
      const float* wp = W + (size_t)(nb * 16 + m) * DIM + k0;
      float4 wlo = *(const float4*)wp;
      float4 whi = *(const float4*)(wp + 4);
      bf16x8 bf = {(__bf16)wlo.x, (__bf16)wlo.y, (__bf16)wlo.z, (__bf16)wlo.w,
                   (__bf16)whi.x, (__bf16)whi.y, (__bf16)whi.z, (__bf16)whi.w};
      acc[nb] = __builtin_amdgcn_mfma_f32_16x16x32_bf16(af, bf, acc[nb], 0, 0, 0);
    }
  }

  float a1v[8], a2v[8];
#pragma unroll
  for (int nb = 0; nb < 8; nb++) {
    a1v[nb] = a[nb * 16 + m];
    a2v[nb] = a[DIM + nb * 16 + m];
  }
  // C/D layout: row = quad*4 + r, col = nb*16 + m
#pragma unroll
  for (int r = 0; r < 4; r++) {
    const int gr = row0 + quad * 4 + r;
    float ps = 0.f, pt = 0.f;
#pragma unroll
    for (int nb = 0; nb < 8; nb++) {
      float e = acc[nb][r];
      ps += e * a1v[nb];
      pt += e * a2v[nb];
      Vt[(size_t)(nb * 16 + m) * NN + gr] = (__bf16)e;
    }
    ps += __shfl_xor(ps, 1); ps += __shfl_xor(ps, 2);
    ps += __shfl_xor(ps, 4); ps += __shfl_xor(ps, 8);
    pt += __shfl_xor(pt, 1); pt += __shfl_xor(pt, 2);
    pt += __shfl_xor(pt, 4); pt += __shfl_xor(pt, 8);
    if (m == 0) { s[gr] = ps * LOG2E; t[gr] = pt * LOG2E; }
  }
}

// ---------------- kernel: TmaxK = max(tK) -----------------------------------
__global__ __launch_bounds__(256) void ktmax(const float* __restrict__ t,
                                             float* __restrict__ tmax) {
  __shared__ float red[4];
  const float4* t4 = (const float4*)t;
  float mx = -3.0e38f;
#pragma unroll
  for (int i = 0; i < NN / 4 / 256; i++) {  // 12 iters, independent loads
    float4 v = t4[i * 256 + threadIdx.x];
    mx = fmaxf(mx, fmaxf(fmaxf(v.x, v.y), fmaxf(v.z, v.w)));
  }
#pragma unroll
  for (int off = 1; off < 64; off <<= 1) mx = fmaxf(mx, __shfl_xor(mx, off));
  if ((threadIdx.x & 63) == 0) red[threadIdx.x >> 6] = mx;
  __syncthreads();
  if (threadIdx.x == 0)
    *tmax = fmaxf(fmaxf(red[0], red[1]), fmaxf(red[2], red[3]));
}

// ---------------- kernel 2: masked softmax + PV, LDS-free --------------------
#define PELS(P, AA0, AA1, T0, T1, SS, MM, LL)                                   \
  {                                                                             \
    float v0 = SS + T0.x, v1 = SS + T0.y, v2 = SS + T0.z, v3 = SS + T0.w;       \
    float v4 = SS + T1.x, v5 = SS + T1.y, v6 = SS + T1.z, v7 = SS + T1.w;       \
    float e0 = (AA0.x != 0) ? __builtin_amdgcn_exp2f(fmaxf(v0, 0.01f * v0) - MM) : 0.f; \
    float e1 = (AA0.y != 0) ? __builtin_amdgcn_exp2f(fmaxf(v1, 0.01f * v1) - MM) : 0.f; \
    float e2 = (AA0.z != 0) ? __builtin_amdgcn_exp2f(fmaxf(v2, 0.01f * v2) - MM) : 0.f; \
    float e3 = (AA0.w != 0) ? __builtin_amdgcn_exp2f(fmaxf(v3, 0.01f * v3) - MM) : 0.f; \
    float e4 = (AA1.x != 0) ? __builtin_amdgcn_exp2f(fmaxf(v4, 0.01f * v4) - MM) : 0.f; \
    float e5 = (AA1.y != 0) ? __builtin_amdgcn_exp2f(fmaxf(v5, 0.01f * v5) - MM) : 0.f; \
    float e6 = (AA1.z != 0) ? __builtin_amdgcn_exp2f(fmaxf(v6, 0.01f * v6) - MM) : 0.f; \
    float e7 = (AA1.w != 0) ? __builtin_amdgcn_exp2f(fmaxf(v7, 0.01f * v7) - MM) : 0.f; \
    LL += ((e0 + e1) + (e2 + e3)) + ((e4 + e5) + (e6 + e7));                    \
    P[0] = (__bf16)e0; P[1] = (__bf16)e1; P[2] = (__bf16)e2; P[3] = (__bf16)e3; \
    P[4] = (__bf16)e4; P[5] = (__bf16)e5; P[6] = (__bf16)e6; P[7] = (__bf16)e7; \
  }

#define FETCH(cc, A0A, A1A, A0B, A1B)                                           \
  {                                                                             \
    const int off = (cc) * BK;                                                  \
    A0A = *(const int4*)(abase + off); A1A = *(const int4*)(abase + off + 4);   \
    A0B = *(const int4*)(bbase + off); A1B = *(const int4*)(bbase + off + 4);   \
  }

#define COMPUTE(cc, A0A, A1A, A0B, A1B)                                         \
  {                                                                             \
    const float* tp = tbase + (cc) * BK;                                        \
    float4 t0 = *(const float4*)tp;                                             \
    float4 t1 = *(const float4*)(tp + 4);                                       \
    const __bf16* vp = vbase + (cc) * BK;                                       \
    bf16x8 pA, pB;                                                              \
    PELS(pA, A0A, A1A, t0, t1, sA, mA, lA)                                      \
    PELS(pB, A0B, A1B, t0, t1, sB, mB, lB)                                      \
    _Pragma("unroll")                                                           \
    for (int nb = 0; nb < 8; nb++) {                                            \
      bf16x8 bv = *(const bf16x8*)(vp + (size_t)(nb * 16) * NN);                \
      accA[nb] = __builtin_amdgcn_mfma_f32_16x16x32_bf16(pA, bv, accA[nb], 0, 0, 0); \
      accB[nb] = __builtin_amdgcn_mfma_f32_16x16x32_bf16(pB, bv, accB[nb], 0, 0, 0); \
    }                                                                           \
  }

__global__ __launch_bounds__(256) void k2_attn(const int* __restrict__ adj,
                                               const __bf16* __restrict__ Vt,
                                               const float* __restrict__ sK,
                                               const float* __restrict__ tK,
                                               const float* __restrict__ tmaxp,
                                               float* __restrict__ part,
                                               float* __restrict__ lpart) {
  const int tid = threadIdx.x;
  const int lane = tid & 63;
  const int wave = tid >> 6;
  const int m = lane & 15;
  const int quad = lane >> 4;
  // XCD-bijective decode: 768 blocks, round-robin XCD -> cs = bid%8 pins one
  // Vt column-slice (393KB) + t-slice per XCD L2.
  const int bid = blockIdx.x;
  const int cs = bid & 7;
  const int xb = bid >> 3;
  const int row0 = xb * 128;
  const int col0 = cs * COLS_PER;
  const int rowA = row0 + wave * 32 + m;
  const int rowB = rowA + 16;

  const float TmaxK = *tmaxp;
  const float sA = sK[rowA], sB = sK[rowB];
  const float uA = sA + TmaxK, uB = sB + TmaxK;
  const float mA = fmaxf(uA, 0.01f * uA);  // exact row softmax shift
  const float mB = fmaxf(uB, 0.01f * uB);

  // quad q owns chunk cols q*8..q*8+7 <-> A-fragment k-slots q*8+j (verified).
  const int* abase = adj + (size_t)rowA * NN + col0 + quad * 8;
  const int* bbase = adj + (size_t)rowB * NN + col0 + quad * 8;
  const float* tbase = tK + col0 + quad * 8;
  const __bf16* vbase = Vt + (size_t)m * NN + col0 + quad * 8;

  f32x4 accA[8], accB[8];
#pragma unroll
  for (int nb = 0; nb < 8; nb++) {
    accA[nb] = (f32x4){0.f, 0.f, 0.f, 0.f};
    accB[nb] = (f32x4){0.f, 0.f, 0.f, 0.f};
  }
  float lA = 0.f, lB = 0.f;

  int4 xA0, xA1, xB0, xB1;
  int4 yA0, yA1, yB0, yB1;

  FETCH(0, xA0, xA1, xB0, xB1);

  for (int c = 0; c < NCHUNK; c += 2) {
    FETCH(c + 1, yA0, yA1, yB0, yB1);
    COMPUTE(c, xA0, xA1, xB0, xB1);
    if (c + 2 < NCHUNK) FETCH(c + 2, xA0, xA1, xB0, xB1);
    COMPUTE(c + 1, yA0, yA1, yB0, yB1);
  }

  // row-sum partials: lanes {m, m+16, m+32, m+48} hold same row
  lA += __shfl_xor(lA, 16); lA += __shfl_xor(lA, 32);
  lB += __shfl_xor(lB, 16); lB += __shfl_xor(lB, 32);
  if (quad == 0) {
    lpart[(size_t)cs * NN + rowA] = lA;
    lpart[(size_t)cs * NN + rowB] = lB;
  }

  // C/D layout: row = quad*4 + r, col = nb*16 + m. Plain stores to partial slice.
  float* po = part + ((size_t)cs * NN + row0 + wave * 32) * DIM;
#pragma unroll
  for (int nb = 0; nb < 8; nb++) {
#pragma unroll
    for (int r = 0; r < 4; r++) {
      po[(size_t)(quad * 4 + r) * DIM + nb * 16 + m] = accA[nb][r];
      po[(size_t)(16 + quad * 4 + r) * DIM + nb * 16 + m] = accB[nb][r];
    }
  }
}

// ---------------- kernel 3: reduce partials + denominators + relu ------------
__global__ __launch_bounds__(256) void k3_fin(const float* __restrict__ part,
                                              const float* __restrict__ lpart,
                                              float* __restrict__ out) {
  __shared__ float li[8];
  const int base = blockIdx.x * 256;       // float4 index base; block = 8 rows
  const int idx = base + (int)threadIdx.x;
  if (threadIdx.x < 8) {
    const int r = (base >> 5) + (int)threadIdx.x;
    float l = 0.f;
#pragma unroll
    for (int c2 = 0; c2 < CSPLIT; c2++) l += lpart[(size_t)c2 * NN + r];
    li[threadIdx.x] = 1.0f / l;
  }
  const float4* p4 = (const float4*)part;
  float4 acc = p4[idx];
#pragma unroll
  for (int c2 = 1; c2 < CSPLIT; c2++) {
    float4 v = p4[(size_t)c2 * (NN * DIM / 4) + idx];
    acc.x += v.x; acc.y += v.y; acc.z += v.z; acc.w += v.w;
  }
  __syncthreads();
  const float liv = li[threadIdx.x >> 5];
  float4 o;
  o.x = fmaxf(acc.x * liv, 0.f);
  o.y = fmaxf(acc.y * liv, 0.f);
  o.z = fmaxf(acc.z * liv, 0.f);
  o.w = fmaxf(acc.w * liv, 0.f);
  ((float4*)out)[idx] = o;
}

extern "C" void kernel_launch(void* const* d_in, const int* in_sizes, int n_in,
                              void* d_out, int out_size, void* d_ws, size_t ws_size,
                              hipStream_t stream) {
  (void)in_sizes; (void)n_in; (void)out_size; (void)ws_size;
  const float* emb = (const float*)d_in[0];
  const int* adj = (const int*)d_in[1];
  const float* W = (const float*)d_in[2];
  const float* a = (const float*)d_in[3];
  float* out = (float*)d_out;

  char* ws = (char*)d_ws;
  __bf16* Vt = (__bf16*)ws;                       // 3,145,728 B
  float* s = (float*)(ws + 3145728);              // 49,152 B (log2e-scaled)
  float* t = (float*)(ws + 3194880);              // 49,152 B (log2e-scaled)
  float* lpart = (float*)(ws + 3244032);          // 8*12288*4 = 393,216 B
  float* tmax = (float*)(ws + 3686400);           // 256 B
  float* part = (float*)(ws + 3686656);           // 8*12288*128*4 = 50,331,648 B

  k1_gemm<<<NN / 64, 256, 0, stream>>>(emb, W, a, Vt, s, t);
  ktmax<<<1, 256, 0, stream>>>(t, tmax);
  k2_attn<<<NN / 128 * CSPLIT, 256, 0, stream>>>(adj, Vt, s, t, tmax, part, lpart);
  k3_fin<<<NN * DIM / 4 / 256, 256, 0, stream>>>(part, lpart, out);
}

// Round 4
// 890.990 us; speedup vs baseline: 1.0751x; 1.0751x over previous
//
#include <hip/hip_runtime.h>

// GraphAttention: N=12288, IN=OUT=128.
// e_new = emb@W.T ; s = e_new@a1 ; t = e_new@a2
// e[i][j] = leaky(s_i + t_j) masked by adj; softmax rows; out = relu(att @ e_new)
//
//  kpack: adj (604 MB int32) -> 1-bit mask (18.9 MB), perfectly coalesced
//         (1KB/wave-inst) + __ballot pack. Pays the mandatory adj read at
//         pure-stream BW instead of inside k2's scattered request mix.
//  k1:   bf16 MFMA gemm emb@W.T -> Vt (bf16, [d][j]); s,t pre-scaled by log2e.
//  ktmax: TmaxK = max_j tK_j.
//  k2:   masked-softmax-PV. Packed adj: 2 u32 + 2 float4 register loads per
//        chunk (was ~256 scattered 16B segments). Vt via global_load_lds
//        4-deep ring. SYNC = round-1's VERIFIED skeleton: DMA 2-3 chunks
//        ahead, vmcnt(6)+s_barrier after every chunk's compute -> 2 barriers
//        between any buffer's last read and its overwrite (round-3's
//        1-barrier/2-chunk variant raced; this one provably doesn't).
//  k3:   reduce col-split partials + denominators + normalize + relu.

#define NN 12288
#define DIM 128
#define CSPLIT 8
#define COLS_PER (NN / CSPLIT)   // 1536
#define BK 32
#define NCHUNK (COLS_PER / BK)   // 48
#define NWPR (NN / 32)           // 384 packed words per row
#define LOG2E 1.4426950408889634f

typedef __bf16 bf16x8 __attribute__((ext_vector_type(8)));
typedef float f32x4 __attribute__((ext_vector_type(4)));

__device__ __forceinline__ void gl_lds16(const __bf16* g, __bf16* l) {
  __builtin_amdgcn_global_load_lds(
      (const __attribute__((address_space(1))) void*)g,
      (__attribute__((address_space(3))) void*)l, 16, 0, 0);
}

// ---------------- kernel 0: bit-pack adjacency ------------------------------
__device__ __forceinline__ unsigned spread4(unsigned b) {
  // 8 bits -> every 4th bit of a 32-bit word
  b = (b | (b << 12)) & 0x000F000Fu;
  b = (b | (b << 6))  & 0x03030303u;
  b = (b | (b << 3))  & 0x11111111u;
  return b;
}

#define PACK_BLOCKS 2048
#define PACK_ITERS (NN * (NN / 32) / (PACK_BLOCKS * 4) / 8)  // 72

__global__ __launch_bounds__(256) void kpack(const int* __restrict__ adj,
                                             unsigned* __restrict__ adjP) {
  const int lane = threadIdx.x & 63;
  const int gw = blockIdx.x * 4 + (threadIdx.x >> 6);  // global wave id
#pragma unroll 4
  for (int it = 0; it < PACK_ITERS; it++) {
    const size_t wb = ((size_t)gw * PACK_ITERS + it) * 8;  // 8 words/wave-iter
    int4 v = *(const int4*)(adj + wb * 32 + lane * 4);     // 1KB contiguous/wave
    unsigned long long bx = __ballot(v.x != 0);
    unsigned long long by = __ballot(v.y != 0);
    unsigned long long bz = __ballot(v.z != 0);
    unsigned long long bw = __ballot(v.w != 0);
    if (lane < 8) {
      unsigned sx = spread4((unsigned)(bx >> (lane * 8)) & 0xFFu);
      unsigned sy = spread4((unsigned)(by >> (lane * 8)) & 0xFFu);
      unsigned sz = spread4((unsigned)(bz >> (lane * 8)) & 0xFFu);
      unsigned sw = spread4((unsigned)(bw >> (lane * 8)) & 0xFFu);
      adjP[wb + lane] = sx | (sy << 1) | (sz << 2) | (sw << 3);
    }
  }
}

// ---------------- kernel 1: e_new = emb @ W.T (bf16 MFMA), emits Vt, sK, tK --
__global__ __launch_bounds__(256) void k1_gemm(const float* __restrict__ emb,
                                               const float* __restrict__ W,
                                               const float* __restrict__ a,
                                               __bf16* __restrict__ Vt,
                                               float* __restrict__ s,
                                               float* __restrict__ t) {
  const int lane = threadIdx.x & 63;
  const int wave = threadIdx.x >> 6;
  const int m = lane & 15;
  const int quad = lane >> 4;
  const int row0 = blockIdx.x * 64 + wave * 16;  // this wave: 16 rows

  f32x4 acc[8];
#pragma unroll
  for (int nb = 0; nb < 8; nb++) acc[nb] = (f32x4){0.f, 0.f, 0.f, 0.f};

#pragma unroll
  for (int ks = 0; ks < 4; ks++) {
    const int k0 = ks * 32 + quad * 8;
    const float* ep = emb + (size_t)(row0 + m) * DIM + k0;
    float4 lo = *(const float4*)ep;
    float4 hi = *(const float4*)(ep + 4);
    bf16x8 af = {(__bf16)lo.x, (__bf16)lo.y, (__bf16)lo.z, (__bf16)lo.w,
                 (__bf16)hi.x, (__bf16)hi.y, (__bf16)hi.z, (__bf16)hi.w};
#pragma unroll
    for (int nb = 0; nb < 8; nb++) {
      const float* wp = W + (size_t)(nb * 16 + m) * DIM + k0;
      float4 wlo = *(const float4*)wp;
      float4 whi = *(const float4*)(wp + 4);
      bf16x8 bf = {(__bf16)wlo.x, (__bf16)wlo.y, (__bf16)wlo.z, (__bf16)wlo.w,
                   (__bf16)whi.x, (__bf16)whi.y, (__bf16)whi.z, (__bf16)whi.w};
      acc[nb] = __builtin_amdgcn_mfma_f32_16x16x32_bf16(af, bf, acc[nb], 0, 0, 0);
    }
  }

  float a1v[8], a2v[8];
#pragma unroll
  for (int nb = 0; nb < 8; nb++) {
    a1v[nb] = a[nb * 16 + m];
    a2v[nb] = a[DIM + nb * 16 + m];
  }
  // C/D layout: row = quad*4 + r, col = nb*16 + m
#pragma unroll
  for (int r = 0; r < 4; r++) {
    const int gr = row0 + quad * 4 + r;
    float ps = 0.f, pt = 0.f;
#pragma unroll
    for (int nb = 0; nb < 8; nb++) {
      float e = acc[nb][r];
      ps += e * a1v[nb];
      pt += e * a2v[nb];
      Vt[(size_t)(nb * 16 + m) * NN + gr] = (__bf16)e;
    }
    ps += __shfl_xor(ps, 1); ps += __shfl_xor(ps, 2);
    ps += __shfl_xor(ps, 4); ps += __shfl_xor(ps, 8);
    pt += __shfl_xor(pt, 1); pt += __shfl_xor(pt, 2);
    pt += __shfl_xor(pt, 4); pt += __shfl_xor(pt, 8);
    if (m == 0) { s[gr] = ps * LOG2E; t[gr] = pt * LOG2E; }
  }
}

// ---------------- kernel: TmaxK = max(tK) -----------------------------------
__global__ __launch_bounds__(256) void ktmax(const float* __restrict__ t,
                                             float* __restrict__ tmax) {
  __shared__ float red[4];
  const float4* t4 = (const float4*)t;
  float mx = -3.0e38f;
#pragma unroll
  for (int i = 0; i < NN / 4 / 256; i++) {  // 12 iters, independent loads
    float4 v = t4[i * 256 + threadIdx.x];
    mx = fmaxf(mx, fmaxf(fmaxf(v.x, v.y), fmaxf(v.z, v.w)));
  }
#pragma unroll
  for (int off = 1; off < 64; off <<= 1) mx = fmaxf(mx, __shfl_xor(mx, off));
  if ((threadIdx.x & 63) == 0) red[threadIdx.x >> 6] = mx;
  __syncthreads();
  if (threadIdx.x == 0)
    *tmax = fmaxf(fmaxf(red[0], red[1]), fmaxf(red[2], red[3]));
}

// ---------------- kernel 2: masked softmax + PV ------------------------------
#define PELS(P, WQ, T0, T1, SS, MM, LL)                                         \
  {                                                                             \
    float v0 = SS + T0.x, v1 = SS + T0.y, v2 = SS + T0.z, v3 = SS + T0.w;       \
    float v4 = SS + T1.x, v5 = SS + T1.y, v6 = SS + T1.z, v7 = SS + T1.w;       \
    float e0 = ((WQ) & 1u)        ? __builtin_amdgcn_exp2f(fmaxf(v0, 0.01f * v0) - MM) : 0.f; \
    float e1 = ((WQ >> 1) & 1u)   ? __builtin_amdgcn_exp2f(fmaxf(v1, 0.01f * v1) - MM) : 0.f; \
    float e2 = ((WQ >> 2) & 1u)   ? __builtin_amdgcn_exp2f(fmaxf(v2, 0.01f * v2) - MM) : 0.f; \
    float e3 = ((WQ >> 3) & 1u)   ? __builtin_amdgcn_exp2f(fmaxf(v3, 0.01f * v3) - MM) : 0.f; \
    float e4 = ((WQ >> 4) & 1u)   ? __builtin_amdgcn_exp2f(fmaxf(v4, 0.01f * v4) - MM) : 0.f; \
    float e5 = ((WQ >> 5) & 1u)   ? __builtin_amdgcn_exp2f(fmaxf(v5, 0.01f * v5) - MM) : 0.f; \
    float e6 = ((WQ >> 6) & 1u)   ? __builtin_amdgcn_exp2f(fmaxf(v6, 0.01f * v6) - MM) : 0.f; \
    float e7 = ((WQ >> 7) & 1u)   ? __builtin_amdgcn_exp2f(fmaxf(v7, 0.01f * v7) - MM) : 0.f; \
    LL += ((e0 + e1) + (e2 + e3)) + ((e4 + e5) + (e6 + e7));                    \
    P[0] = (__bf16)e0; P[1] = (__bf16)e1; P[2] = (__bf16)e2; P[3] = (__bf16)e3; \
    P[4] = (__bf16)e4; P[5] = (__bf16)e5; P[6] = (__bf16)e6; P[7] = (__bf16)e7; \
  }

#define DMA2(cc)                                                                \
  {                                                                             \
    __bf16* d = &vtb[(cc) & 3][dst0];                                           \
    gl_lds16(vsrc0 + (size_t)(cc) * BK, d);                                     \
    gl_lds16(vsrc1 + (size_t)(cc) * BK, d + 512);                               \
  }

// regs for one chunk cc: 2 u32 adj words + 2 float4 t  (4 VMEM ops)
#define FETCHP(cc, WA, WB, T0, T1)                                              \
  {                                                                             \
    WA = apA[(cc)];                                                             \
    WB = apB[(cc)];                                                             \
    const float* tp = tbase + (cc) * BK;                                        \
    T0 = *(const float4*)tp;  T1 = *(const float4*)(tp + 4);                    \
  }

#define COMPC(cc, WA, WB, T0, T1)                                               \
  {                                                                             \
    const unsigned wqA = (WA) >> qsh;                                           \
    const unsigned wqB = (WB) >> qsh;                                           \
    const __bf16* vb = &vtb[(cc) & 3][vread];                                   \
    bf16x8 pA, pB;                                                              \
    PELS(pA, wqA, T0, T1, sA, mA, lA)                                           \
    PELS(pB, wqB, T0, T1, sB, mB, lB)                                           \
    _Pragma("unroll")                                                           \
    for (int nb = 0; nb < 8; nb++) {                                            \
      bf16x8 bv = *(const bf16x8*)(vb + nb * 512);                              \
      accA[nb] = __builtin_amdgcn_mfma_f32_16x16x32_bf16(pA, bv, accA[nb], 0, 0, 0); \
      accB[nb] = __builtin_amdgcn_mfma_f32_16x16x32_bf16(pB, bv, accB[nb], 0, 0, 0); \
    }                                                                           \
  }

#define WAIT6 { asm volatile("s_waitcnt vmcnt(6)" ::: "memory"); __builtin_amdgcn_s_barrier(); }

__global__ __launch_bounds__(256, 3) void k2_attn(const unsigned* __restrict__ adjP,
                                                  const __bf16* __restrict__ Vt,
                                                  const float* __restrict__ sK,
                                                  const float* __restrict__ tK,
                                                  const float* __restrict__ tmaxp,
                                                  float* __restrict__ part,
                                                  float* __restrict__ lpart) {
  // 4-deep ring of Vt tiles: 128 dims x 32 cols bf16 = 8KB each, XOR-swizzled.
  __shared__ __attribute__((aligned(16))) __bf16 vtb[4][4096];

  const int tid = threadIdx.x;
  const int lane = tid & 63;
  const int wave = tid >> 6;
  const int m = lane & 15;
  const int quad = lane >> 4;
  const int qsh = quad * 8;
  const int bid = blockIdx.x;
  const int cs = bid & 7;      // XCD-bijective: 768 blocks, cs pins L2 slice
  const int xb = bid >> 3;
  const int row0 = xb * 128;
  const int col0 = cs * COLS_PER;
  const int rowA = row0 + wave * 32 + m;
  const int rowB = rowA + 16;

  const float TmaxK = *tmaxp;
  const float sA = sK[rowA], sB = sK[rowB];
  const float uA = sA + TmaxK, uB = sB + TmaxK;
  const float mA = fmaxf(uA, 0.01f * uA);  // exact row softmax shift
  const float mB = fmaxf(uB, 0.01f * uB);

  // DMA source swizzle (round-1, verified): LDS slot p (16B) = wave*128+lane;
  // row = p>>2, cg' = p&3, source colgrp = cg' ^ ((row>>1)&3).
  const int p0 = wave * 128 + lane;
  const int r0d = p0 >> 2;
  const int cg0 = (p0 & 3) ^ ((r0d >> 1) & 3);
  const __bf16* vsrc0 = Vt + (size_t)r0d * NN + col0 + cg0 * 8;
  const __bf16* vsrc1 = vsrc0 + (size_t)16 * NN;
  const int dst0 = wave * 1024;
  // fragment read: row=nb*16+m, colgrp=quad -> slot row*4 + (quad^((m>>1)&3))
  const int vread = (m * 4 + (quad ^ ((m >> 1) & 3))) * 8;

  const unsigned* apA = adjP + (size_t)rowA * NWPR + cs * (COLS_PER / 32);
  const unsigned* apB = adjP + (size_t)rowB * NWPR + cs * (COLS_PER / 32);
  const float* tbase = tK + col0 + quad * 8;

  f32x4 accA[8], accB[8];
#pragma unroll
  for (int nb = 0; nb < 8; nb++) {
    accA[nb] = (f32x4){0.f, 0.f, 0.f, 0.f};
    accB[nb] = (f32x4){0.f, 0.f, 0.f, 0.f};
  }
  float lA = 0.f, lB = 0.f;

  unsigned wXa, wXb, wYa, wYb;
  float4 tX0, tX1, tY0, tY1;

  // prologue: DMA chunks 0,1 (2 ahead); regs chunk 0; drain DMA(0); publish.
  DMA2(0); DMA2(1);
  FETCHP(0, wXa, wXb, tX0, tX1);
  WAIT6;   // leaves DMA2(1)+FETCHP(0) in flight; DMA2(0) landed for all waves

  for (int c = 0; c < NCHUNK; c += 2) {
    // half A: compute chunk c (X); DMA c+2; regs c+1 (Y)
    if (c + 2 < NCHUNK) DMA2(c + 2);       // buffer (c+2)&3: last read chunk c-2,
                                           // 2 barriers back -> race-free
    FETCHP(c + 1, wYa, wYb, tY0, tY1);
    COMPC(c, wXa, wXb, tX0, tX1);
    WAIT6;   // drains DMA2(c+1) (needed next) + all older; keeps this half's 6

    // half B: compute chunk c+1 (Y); DMA c+3; regs c+2 (X)
    if (c + 3 < NCHUNK) DMA2(c + 3);
    if (c + 2 < NCHUNK) FETCHP(c + 2, wXa, wXb, tX0, tX1);
    COMPC(c + 1, wYa, wYb, tY0, tY1);
    if (c + 2 < NCHUNK) WAIT6;             // drains DMA2(c+2) for next half A
  }

  // row-sum partials: lanes {m, m+16, m+32, m+48} hold same row
  lA += __shfl_xor(lA, 16); lA += __shfl_xor(lA, 32);
  lB += __shfl_xor(lB, 16); lB += __shfl_xor(lB, 32);
  if (quad == 0) {
    lpart[(size_t)cs * NN + rowA] = lA;
    lpart[(size_t)cs * NN + rowB] = lB;
  }

  // C/D layout: row = quad*4 + r, col = nb*16 + m. Plain stores to partial slice.
  float* po = part + ((size_t)cs * NN + row0 + wave * 32) * DIM;
#pragma unroll
  for (int nb = 0; nb < 8; nb++) {
#pragma unroll
    for (int r = 0; r < 4; r++) {
      po[(size_t)(quad * 4 + r) * DIM + nb * 16 + m] = accA[nb][r];
      po[(size_t)(16 + quad * 4 + r) * DIM + nb * 16 + m] = accB[nb][r];
    }
  }
}

// ---------------- kernel 3: reduce partials + denominators + relu ------------
__global__ __launch_bounds__(256) void k3_fin(const float* __restrict__ part,
                                              const float* __restrict__ lpart,
                                              float* __restrict__ out) {
  __shared__ float li[8];
  const int base = blockIdx.x * 256;       // float4 index base; block = 8 rows
  const int idx = base + (int)threadIdx.x;
  if (threadIdx.x < 8) {
    const int r = (base >> 5) + (int)threadIdx.x;
    float l = 0.f;
#pragma unroll
    for (int c2 = 0; c2 < CSPLIT; c2++) l += lpart[(size_t)c2 * NN + r];
    li[threadIdx.x] = 1.0f / l;
  }
  const float4* p4 = (const float4*)part;
  float4 acc = p4[idx];
#pragma unroll
  for (int c2 = 1; c2 < CSPLIT; c2++) {
    float4 v = p4[(size_t)c2 * (NN * DIM / 4) + idx];
    acc.x += v.x; acc.y += v.y; acc.z += v.z; acc.w += v.w;
  }
  __syncthreads();
  const float liv = li[threadIdx.x >> 5];
  float4 o;
  o.x = fmaxf(acc.x * liv, 0.f);
  o.y = fmaxf(acc.y * liv, 0.f);
  o.z = fmaxf(acc.z * liv, 0.f);
  o.w = fmaxf(acc.w * liv, 0.f);
  ((float4*)out)[idx] = o;
}

extern "C" void kernel_launch(void* const* d_in, const int* in_sizes, int n_in,
                              void* d_out, int out_size, void* d_ws, size_t ws_size,
                              hipStream_t stream) {
  (void)in_sizes; (void)n_in; (void)out_size; (void)ws_size;
  const float* emb = (const float*)d_in[0];
  const int* adj = (const int*)d_in[1];
  const float* W = (const float*)d_in[2];
  const float* a = (const float*)d_in[3];
  float* out = (float*)d_out;

  char* ws = (char*)d_ws;
  __bf16* Vt = (__bf16*)ws;                       // 3,145,728 B
  float* s = (float*)(ws + 3145728);              // 49,152 B (log2e-scaled)
  float* t = (float*)(ws + 3194880);              // 49,152 B (log2e-scaled)
  float* lpart = (float*)(ws + 3244032);          // 393,216 B
  float* tmax = (float*)(ws + 3686400);           // 256 B
  float* part = (float*)(ws + 3686656);           // 50,331,648 B
  unsigned* adjP = (unsigned*)(ws + 54018304);    // 18,874,368 B packed adj

  kpack<<<PACK_BLOCKS, 256, 0, stream>>>(adj, adjP);
  k1_gemm<<<NN / 64, 256, 0, stream>>>(emb, W, a, Vt, s, t);
  ktmax<<<1, 256, 0, stream>>>(t, tmax);
  k2_attn<<<NN / 128 * CSPLIT, 256, 0, stream>>>(adjP, Vt, s, t, tmax, part, lpart);
  k3_fin<<<NN * DIM / 4 / 256, 256, 0, stream>>>(part, lpart, out);
}

// Round 5
// 829.657 us; speedup vs baseline: 1.1545x; 1.0739x over previous
//
#include <hip/hip_runtime.h>

// GraphAttention: N=12288, IN=OUT=128.
// e_new = emb@W.T ; s = e_new@a1 ; t = e_new@a2
// e[i][j] = leaky(s_i + t_j) masked by adj; softmax rows; out = relu(att @ e_new)
//
// ROOFLINE NOTE (rounds 0-4): dur_us carries ~746us of harness re-poison
// (2x 2.36GB fills @ 80% HBM peak, visible as the top-5 dispatches every
// round). Our 5-kernel chain is ~85us, at the mandatory-traffic floor:
// adj 604MB read (L3-assisted ~62us) + part 100MB r/w (~16us) + misc.
// Experiments confirming the floor: LDS-free k2 (+125us, scattered L2
// reads); packed-adj kpack (+58us net: extra 604MB pass costs more than
// k2's saving since L3 absorbs ~40% of adj re-reads). This file is the
// best-measured variant, restored.
//
//  k1: bf16 MFMA gemm emb@W.T -> Vt (bf16, transposed [d][j]), s[], t[] (fp32)
//  ktmax: Tmax = max_j t_j (fixed per-row softmax shift; softmax partials add)
//  k2: streaming masked-softmax-PV. adj + Vt staged through LDS with fully
//      COALESCED global loads; A-fragment scatter reads LDS. Double-buffered
//      chunks, 1 barrier/chunk, prefetch issued before compute. 8 col-splits,
//      partials to ws (no atomics).
//  kl: combine softmax-denominator partials -> 1/l per row
//  k3: out = relu( (sum of partials) * linv )

#define NN 12288
#define DIM 128
#define CSPLIT 8
#define COLS_PER (NN / CSPLIT)   // 1536
#define BK 32
#define NCHUNK (COLS_PER / BK)   // 48

typedef __bf16 bf16x8 __attribute__((ext_vector_type(8)));
typedef float f32x4 __attribute__((ext_vector_type(4)));

// ---------------- kernel 1: e_new = emb @ W.T (bf16 MFMA), emits Vt, s, t ----
__global__ __launch_bounds__(256) void k1_gemm(const float* __restrict__ emb,
                                               const float* __restrict__ W,
                                               const float* __restrict__ a,
                                               __bf16* __restrict__ Vt,
                                               float* __restrict__ s,
                                               float* __restrict__ t) {
  const int lane = threadIdx.x & 63;
  const int wave = threadIdx.x >> 6;
  const int m = lane & 15;
  const int quad = lane >> 4;
  const int row0 = blockIdx.x * 64 + wave * 16;  // this wave: 16 rows

  f32x4 acc[8];
#pragma unroll
  for (int nb = 0; nb < 8; nb++) acc[nb] = (f32x4){0.f, 0.f, 0.f, 0.f};

#pragma unroll
  for (int ks = 0; ks < 4; ks++) {
    const int k0 = ks * 32 + quad * 8;
    const float* ep = emb + (size_t)(row0 + m) * DIM + k0;
    float4 lo = *(const float4*)ep;
    float4 hi = *(const float4*)(ep + 4);
    bf16x8 af = {(__bf16)lo.x, (__bf16)lo.y, (__bf16)lo.z, (__bf16)lo.w,
                 (__bf16)hi.x, (__bf16)hi.y, (__bf16)hi.z, (__bf16)hi.w};
#pragma unroll
    for (int nb = 0; nb < 8; nb++) {
      const float* wp = W + (size_t)(nb * 16 + m) * DIM + k0;
      float4 wlo = *(const float4*)wp;
      float4 whi = *(const float4*)(wp + 4);
      bf16x8 bf = {(__bf16)wlo.x, (__bf16)wlo.y, (__bf16)wlo.z, (__bf16)wlo.w,
                   (__bf16)whi.x, (__bf16)whi.y, (__bf16)whi.z, (__bf16)whi.w};
      acc[nb] = __builtin_amdgcn_mfma_f32_16x16x32_bf16(af, bf, acc[nb], 0, 0, 0);
    }
  }

  float a1v[8], a2v[8];
#pragma unroll
  for (int nb = 0; nb < 8; nb++) {
    a1v[nb] = a[nb * 16 + m];
    a2v[nb] = a[DIM + nb * 16 + m];
  }
  // C/D layout: row = quad*4 + r, col = nb*16 + m
#pragma unroll
  for (int r = 0; r < 4; r++) {
    const int gr = row0 + quad * 4 + r;
    float ps = 0.f, pt = 0.f;
#pragma unroll
    for (int nb = 0; nb < 8; nb++) {
      float e = acc[nb][r];
      ps += e * a1v[nb];
      pt += e * a2v[nb];
      Vt[(size_t)(nb * 16 + m) * NN + gr] = (__bf16)e;
    }
    ps += __shfl_xor(ps, 1); ps += __shfl_xor(ps, 2);
    ps += __shfl_xor(ps, 4); ps += __shfl_xor(ps, 8);
    pt += __shfl_xor(pt, 1); pt += __shfl_xor(pt, 2);
    pt += __shfl_xor(pt, 4); pt += __shfl_xor(pt, 8);
    if (m == 0) { s[gr] = ps; t[gr] = pt; }
  }
}

// ---------------- kernel: Tmax = max(t) ------------------------------------
__global__ __launch_bounds__(256) void ktmax(const float* __restrict__ t,
                                             float* __restrict__ tmax) {
  __shared__ float red[256];
  float mx = -1e30f;
  for (int i = threadIdx.x; i < NN; i += 256) mx = fmaxf(mx, t[i]);
  red[threadIdx.x] = mx;
  __syncthreads();
  for (int off = 128; off; off >>= 1) {
    if ((int)threadIdx.x < off) red[threadIdx.x] = fmaxf(red[threadIdx.x], red[threadIdx.x + off]);
    __syncthreads();
  }
  if (threadIdx.x == 0) *tmax = red[0];
}

// ---------------- kernel 2: masked softmax + PV, LDS-staged -----------------
__global__ __launch_bounds__(256, 3) void k2_attn(const int* __restrict__ adj,
                                                  const __bf16* __restrict__ Vt,
                                                  const float* __restrict__ s,
                                                  const float* __restrict__ t,
                                                  const float* __restrict__ tmaxp,
                                                  float* __restrict__ part,
                                                  float* __restrict__ lpart) {
  // adj tile: 128 rows x 32 cols, 1 byte/elem, row stride 40 B (5 ulongs)
  __shared__ unsigned long long adjb[2][128][5];
  // Vt tile: 128 dims x 32 cols bf16, row stride 80 B (16B-aligned: 80=5*16)
  __shared__ __attribute__((aligned(16))) __bf16 vtb[2][128][40];

  const int tid = threadIdx.x;
  const int lane = tid & 63;
  const int wave = tid >> 6;
  const int m = lane & 15;
  const int quad = lane >> 4;
  const int row0 = blockIdx.x * 128;
  const int cs = blockIdx.y;
  const int col0 = cs * COLS_PER;
  const int rowA = row0 + wave * 32 + m;
  const int rowB = rowA + 16;

  const float Tmax = *tmaxp;
  const float sA = s[rowA], sB = s[rowB];
  const float uA = sA + Tmax, uB = sB + Tmax;
  const float mA = fmaxf(uA, 0.01f * uA);  // per-row fixed softmax shift (upper bound)
  const float mB = fmaxf(uB, 0.01f * uB);

  f32x4 accA[8], accB[8];
#pragma unroll
  for (int nb = 0; nb < 8; nb++) {
    accA[nb] = (f32x4){0.f, 0.f, 0.f, 0.f};
    accB[nb] = (f32x4){0.f, 0.f, 0.f, 0.f};
  }
  float lA = 0.f, lB = 0.f;

  // staging registers (global -> reg -> LDS)
  int4 ga[4];
  bf16x8 gv[2];
  const int fr = tid >> 3, fc = (tid & 7) * 4;  // adj: 8 rows x 128 B per inst
  const int vd = tid >> 2, vc = (tid & 3) * 8;  // Vt: 16 rows x 64 B per inst

  auto fetch = [&](int c) {
    const int cc = col0 + c * BK;
#pragma unroll
    for (int p = 0; p < 4; p++)
      ga[p] = *(const int4*)(adj + (size_t)(row0 + fr + p * 32) * NN + cc + fc);
#pragma unroll
    for (int p = 0; p < 2; p++)
      gv[p] = *(const bf16x8*)(Vt + (size_t)(vd + p * 64) * NN + cc + vc);
  };
  auto commit = [&](int b) {
#pragma unroll
    for (int p = 0; p < 4; p++) {
      unsigned pk = (unsigned)(ga[p].x != 0) | ((unsigned)(ga[p].y != 0) << 8) |
                    ((unsigned)(ga[p].z != 0) << 16) | ((unsigned)(ga[p].w != 0) << 24);
      *(unsigned*)((unsigned char*)&adjb[b][fr + p * 32][0] + fc) = pk;
    }
#pragma unroll
    for (int p = 0; p < 2; p++)
      *(bf16x8*)&vtb[b][vd + p * 64][vc] = gv[p];
  };

  fetch(0);
  commit(0);
  __syncthreads();

  for (int c = 0; c < NCHUNK; c++) {
    if (c + 1 < NCHUNK) fetch(c + 1);

    // ---- compute on buffer c&1 ----
    const int b = c & 1;
    const float* tp = t + col0 + c * BK + quad * 8;
    float4 ct0 = *(const float4*)tp;
    float4 ct1 = *(const float4*)(tp + 4);
    unsigned long long avA = adjb[b][wave * 32 + m][quad];
    unsigned long long avB = adjb[b][wave * 32 + 16 + m][quad];

    bf16x8 pA, pB;
#define PEL(frag, jj, tv, av, ss, mm, ll)                               \
    {                                                                   \
      float v = (ss) + (tv);                                            \
      float lv = fmaxf(v, 0.01f * v);                                   \
      float e = (((av) >> (8 * (jj))) & 1) ? __expf(lv - (mm)) : 0.f;   \
      (ll) += e;                                                        \
      frag[jj] = (__bf16)e;                                             \
    }
    PEL(pA, 0, ct0.x, avA, sA, mA, lA)
    PEL(pA, 1, ct0.y, avA, sA, mA, lA)
    PEL(pA, 2, ct0.z, avA, sA, mA, lA)
    PEL(pA, 3, ct0.w, avA, sA, mA, lA)
    PEL(pA, 4, ct1.x, avA, sA, mA, lA)
    PEL(pA, 5, ct1.y, avA, sA, mA, lA)
    PEL(pA, 6, ct1.z, avA, sA, mA, lA)
    PEL(pA, 7, ct1.w, avA, sA, mA, lA)
    PEL(pB, 0, ct0.x, avB, sB, mB, lB)
    PEL(pB, 1, ct0.y, avB, sB, mB, lB)
    PEL(pB, 2, ct0.z, avB, sB, mB, lB)
    PEL(pB, 3, ct0.w, avB, sB, mB, lB)
    PEL(pB, 4, ct1.x, avB, sB, mB, lB)
    PEL(pB, 5, ct1.y, avB, sB, mB, lB)
    PEL(pB, 6, ct1.z, avB, sB, mB, lB)
    PEL(pB, 7, ct1.w, avB, sB, mB, lB)
#undef PEL

#pragma unroll
    for (int nb = 0; nb < 8; nb++) {
      bf16x8 bv = *(const bf16x8*)&vtb[b][nb * 16 + m][quad * 8];
      accA[nb] = __builtin_amdgcn_mfma_f32_16x16x32_bf16(pA, bv, accA[nb], 0, 0, 0);
      accB[nb] = __builtin_amdgcn_mfma_f32_16x16x32_bf16(pB, bv, accB[nb], 0, 0, 0);
    }

    if (c + 1 < NCHUNK) commit((c + 1) & 1);
    __syncthreads();
  }

  // row-sum partials: lanes {m, m+16, m+32, m+48} hold same row
  lA += __shfl_xor(lA, 16); lA += __shfl_xor(lA, 32);
  lB += __shfl_xor(lB, 16); lB += __shfl_xor(lB, 32);
  if (quad == 0) {
    lpart[(size_t)cs * NN + rowA] = lA;
    lpart[(size_t)cs * NN + rowB] = lB;
  }

  // C/D layout: row = quad*4 + r, col = nb*16 + m. Plain stores to partial slice.
  float* po = part + ((size_t)cs * NN + row0 + wave * 32) * DIM;
#pragma unroll
  for (int nb = 0; nb < 8; nb++) {
#pragma unroll
    for (int r = 0; r < 4; r++) {
      po[(size_t)(quad * 4 + r) * DIM + nb * 16 + m] = accA[nb][r];
      po[(size_t)(16 + quad * 4 + r) * DIM + nb * 16 + m] = accB[nb][r];
    }
  }
}

// ---------------- kernel: combine denominator partials ----------------------
__global__ __launch_bounds__(256) void kl(const float* __restrict__ lpart,
                                          float* __restrict__ linv) {
  const int r = blockIdx.x * 256 + threadIdx.x;  // 48 blocks
  float l = 0.f;
#pragma unroll
  for (int cs = 0; cs < CSPLIT; cs++) l += lpart[(size_t)cs * NN + r];
  linv[r] = 1.0f / l;
}

// ---------------- kernel 3: reduce partials + normalize + relu ---------------
__global__ __launch_bounds__(256) void k3_fin(const float* __restrict__ part,
                                              const float* __restrict__ linv,
                                              float* __restrict__ out) {
  const int idx = blockIdx.x * 256 + threadIdx.x;  // over NN*DIM/4
  const int row = idx >> 5;                        // DIM/4 = 32 float4 per row
  const float4* p4 = (const float4*)part;
  float4 acc = p4[idx];
#pragma unroll
  for (int cs = 1; cs < CSPLIT; cs++) {
    float4 v = p4[(size_t)cs * (NN * DIM / 4) + idx];
    acc.x += v.x; acc.y += v.y; acc.z += v.z; acc.w += v.w;
  }
  const float li = linv[row];
  float4 o;
  o.x = fmaxf(acc.x * li, 0.f);
  o.y = fmaxf(acc.y * li, 0.f);
  o.z = fmaxf(acc.z * li, 0.f);
  o.w = fmaxf(acc.w * li, 0.f);
  ((float4*)out)[idx] = o;
}

extern "C" void kernel_launch(void* const* d_in, const int* in_sizes, int n_in,
                              void* d_out, int out_size, void* d_ws, size_t ws_size,
                              hipStream_t stream) {
  (void)in_sizes; (void)n_in; (void)out_size; (void)ws_size;
  const float* emb = (const float*)d_in[0];
  const int* adj = (const int*)d_in[1];
  const float* W = (const float*)d_in[2];
  const float* a = (const float*)d_in[3];
  float* out = (float*)d_out;

  char* ws = (char*)d_ws;
  __bf16* Vt = (__bf16*)ws;                       // 3,145,728 B
  float* s = (float*)(ws + 3145728);              // 49,152 B
  float* t = (float*)(ws + 3194880);              // 49,152 B
  float* lpart = (float*)(ws + 3244032);          // 8*12288*4 = 393,216 B
  float* linv = (float*)(ws + 3637248);           // 49,152 B
  float* tmax = (float*)(ws + 3686400);           // 256 B
  float* part = (float*)(ws + 3686656);           // 8*12288*128*4 = 50,331,648 B

  k1_gemm<<<NN / 64, 256, 0, stream>>>(emb, W, a, Vt, s, t);
  ktmax<<<1, 256, 0, stream>>>(t, tmax);
  dim3 g2(NN / 128, CSPLIT);
  k2_attn<<<g2, 256, 0, stream>>>(adj, Vt, s, t, tmax, part, lpart);
  kl<<<NN / 256, 256, 0, stream>>>(lpart, linv);
  k3_fin<<<NN * DIM / 4 / 256, 256, 0, stream>>>(part, linv, out);
}